// Round 8
// baseline (202.097 us; speedup 1.0000x reference)
//
#include <hip/hip_runtime.h>
#include <math.h>

#define N_NODES 4096
#define N_EDGES 8192
#define N_GRAPHS 256
#define D_NODE 64
#define D_EDGE 32
#define HH 256

#define K1 2176   // 33*64 (edge-MLP + nn_b rows) + 64 (x augment for root1)
#define K2 8704   // 33*256 + 256 (h augment for root2)
#define NSL1 8    // split-K slices conv1 (grid 2x64x8 = 1024 blocks = 4/CU)
#define NSL2 10   // split-K slices conv2 (grid 2x64x10 = 1280 blocks = 5/CU)

typedef _Float16 half8v __attribute__((ext_vector_type(8)));
typedef _Float16 half4v __attribute__((ext_vector_type(4)));
typedef float floatx4 __attribute__((ext_vector_type(4)));

// ---------------- workspace layout (float offsets) ----------------
static const size_t OFF_S    = 0;              // S fp16: 4096 x 8704 halves = 17,825,792 floats (S1 shares)
static const size_t OFF_BT1  = 17825792;       // BT1 fp16: 256 x 2176 halves = 278,528 floats
static const size_t OFF_BT2  = 18104320;       // BT2 fp16: 256 x 8704 halves = 1,114,112 floats
static const size_t OFF_CP   = 19218432;       // Cpart fp16: 10 x 4096 x 256 halves = 5,242,880 floats
static const size_t OFF_H    = 24461312;       // h fp16: 524,288 floats
static const size_t OFF_INT  = 24985600;       // starts[4097] + pad + elist[8192]
// total ~100 MB

// ---------------- prep: CSR build (block 0) + weight pack (other blocks) ----------------
__device__ void csr_body(const int* __restrict__ dst,
                         int* __restrict__ starts,
                         int* __restrict__ elist) {
    __shared__ int cnt[4096];
    __shared__ int ps[256];
    int t = threadIdx.x;
#pragma unroll
    for (int i = 0; i < 16; ++i) cnt[t * 16 + i] = 0;
    __syncthreads();
#pragma unroll
    for (int i = 0; i < 32; ++i) atomicAdd(&cnt[dst[i * 256 + t]], 1);
    __syncthreads();
    int v[16]; int s = 0;
#pragma unroll
    for (int i = 0; i < 16; ++i) { v[i] = cnt[t * 16 + i]; s += v[i]; }
    ps[t] = s;
    __syncthreads();
    for (int off = 1; off < 256; off <<= 1) {
        int tv = (t >= off) ? ps[t - off] : 0;
        __syncthreads();
        ps[t] += tv;
        __syncthreads();
    }
    int excl = ps[t] - s;
#pragma unroll
    for (int i = 0; i < 16; ++i) {
        starts[t * 16 + i] = excl;
        cnt[t * 16 + i] = excl;       // becomes cursor
        excl += v[i];
    }
    if (t == 255) starts[4096] = excl;
    __syncthreads();
#pragma unroll
    for (int i = 0; i < 32; ++i) {
        int e = i * 256 + t;
        int d = dst[e];
        int p = atomicAdd(&cnt[d], 1);
        elist[p] = e;
    }
}

__device__ void packT_body(const float* __restrict__ w,
                           const float* __restrict__ b,
                           const float* __restrict__ rw,
                           _Float16* __restrict__ BT,
                           int kk0, int o0, int K,
                           int wlim, int blim, int wshift, int wmask, int wrow) {
    __shared__ float T[64][65];
    int t = threadIdx.x;
    int ol = t & 63, kb = t >> 6;
#pragma unroll
    for (int p = 0; p < 16; ++p) {
        int kl = p * 4 + kb;
        int kk = kk0 + kl, o = o0 + ol;
        float v;
        if (kk < wlim)      v = w[(kk >> wshift) * wrow + (kk & wmask) * 256 + o];
        else if (kk < blim) v = b[(kk - wlim) * 256 + o];
        else                v = rw[(kk - blim) * 256 + o];
        T[kl][ol] = v;
    }
    __syncthreads();
    int kl2 = t & 63, ob = t >> 6;
#pragma unroll
    for (int p = 0; p < 16; ++p) {
        int ol2 = p * 4 + ob;
        BT[(size_t)(o0 + ol2) * K + kk0 + kl2] = (_Float16)T[kl2][ol2];
    }
}

__global__ __launch_bounds__(256) void prep_k(const int* __restrict__ dst,
                                              int* __restrict__ starts,
                                              int* __restrict__ elist,
                                              const float* __restrict__ w1,
                                              const float* __restrict__ b1,
                                              const float* __restrict__ r1,
                                              const float* __restrict__ w2,
                                              const float* __restrict__ b2,
                                              const float* __restrict__ r2,
                                              _Float16* __restrict__ BT1,
                                              _Float16* __restrict__ BT2) {
    int bx = blockIdx.x, by = blockIdx.y;
    if (bx == 0) {
        if (by == 0) csr_body(dst, starts, elist);
        return;
    }
    int pbx = bx - 1, o0 = by * 64;
    if (pbx < K1 / 64)
        packT_body(w1, b1, r1, BT1, pbx * 64, o0, K1, 2048, 2112, 6, 63, 16384);
    else
        packT_body(w2, b2, r2, BT2, (pbx - K1 / 64) * 64, o0, K2, 8192, 8448, 8, 255, 65536);
}

// ---------------- node outer-product accumulation (fp16 out, augmented) ----------------
// S1[n, k*64+i] = sum_{e:dst=n} ea'[e,k]*x[src[e],i];  S1[n, 2112+i] = x[n,i]
__global__ __launch_bounds__(64) void s1_k(const float* __restrict__ x,
                                           const float* __restrict__ ea,
                                           const int* __restrict__ src,
                                           const int* __restrict__ starts,
                                           const int* __restrict__ elist,
                                           _Float16* __restrict__ S) {
    int n = blockIdx.x, t = threadIdx.x;
    __shared__ float sea[33];
    if (t == 32) sea[32] = 1.0f;
    float acc[33];
#pragma unroll
    for (int k = 0; k < 33; ++k) acc[k] = 0.f;
    int st = starts[n], en = starts[n + 1];
    for (int idx = st; idx < en; ++idx) {
        int e = elist[idx];
        int sn = src[e];
        if (t < 32) sea[t] = ea[e * 32 + t];
        __syncthreads();
        float xv = x[sn * 64 + t];
#pragma unroll
        for (int k = 0; k < 33; ++k) acc[k] += sea[k] * xv;
        __syncthreads();
    }
    _Float16* row = S + (size_t)n * K1;
#pragma unroll
    for (int k = 0; k < 33; ++k) row[k * 64 + t] = (_Float16)acc[k];
    row[2112 + t] = (_Float16)x[n * 64 + t];
}

// S2[n, k*256+i] = sum_{e:dst=n} ea'[e,k]*h[src[e],i];  S2[n, 8448+i] = h[n,i]
__global__ __launch_bounds__(256) void s2_k(const _Float16* __restrict__ h,
                                            const float* __restrict__ ea,
                                            const int* __restrict__ src,
                                            const int* __restrict__ starts,
                                            const int* __restrict__ elist,
                                            _Float16* __restrict__ S) {
    int n = blockIdx.x, t = threadIdx.x;
    __shared__ float sea[33];
    if (t == 32) sea[32] = 1.0f;
    float acc[33];
#pragma unroll
    for (int k = 0; k < 33; ++k) acc[k] = 0.f;
    int st = starts[n], en = starts[n + 1];
    for (int idx = st; idx < en; ++idx) {
        int e = elist[idx];
        int sn = src[e];
        if (t < 32) sea[t] = ea[e * 32 + t];
        __syncthreads();
        float hv = (float)h[sn * 256 + t];
#pragma unroll
        for (int k = 0; k < 33; ++k) acc[k] += sea[k] * hv;
        __syncthreads();
    }
    _Float16* row = S + (size_t)n * K2;
#pragma unroll
    for (int k = 0; k < 33; ++k) row[k * 256 + t] = (_Float16)acc[k];
    row[8448 + t] = h[n * 256 + t];
}

// ---------------- MFMA fp16 GEMM, BM=64 x BN=128, BK=64, split-K, fp16 partials ----------------
// Small tile -> 24 KB LDS -> up to 6 blocks/CU co-resident; more independent waves
// overlap each other's staging drains (the r5 structure was drain-latency-bound at 3/CU).
// Wave w: full 64 M-rows x 32 N-cols (acc 4x2 frags). Staging swizzle: chunk^(row%8).
__device__ __forceinline__ void async_copy16(const void* g, void* l) {
    __builtin_amdgcn_global_load_lds(
        (__attribute__((address_space(1))) unsigned int*)(g),
        (__attribute__((address_space(3))) unsigned int*)(l), 16, 0, 0);
}

__global__ __launch_bounds__(256, 5) void gemm_f16(const _Float16* __restrict__ A,
                                                   const _Float16* __restrict__ BT,
                                                   _Float16* __restrict__ Cpart,
                                                   int K, int NC, int Z) {
    __shared__ _Float16 lds[12288];    // 24 KB: As 64x64 (8 KB) + Bs 128x64 (16 KB); epilogue reuses (64x136)
    _Float16* As = lds;
    _Float16* Bs = lds + 64 * 64;
    int tid = threadIdx.x;
    int w = tid >> 6, l = tid & 63;
    int nt = blockIdx.x, mt = blockIdx.y, z = blockIdx.z;
    int c0 = z * NC / Z, c1 = (z + 1) * NC / Z;
    int k0 = c0 * 64;

    // staging: wave w stages A rows [w*16, w*16+16) and B rows [w*32, w*32+32)
    int lr = l >> 3, lc = l & 7;
    int gc = lc ^ lr;                  // global chunk landing in slot lc of row (..+lr)
    const _Float16* gA0 = A  + (size_t)(mt * 64 + w * 16 + lr) * K + k0 + gc * 8;
    const _Float16* gB0 = BT + (size_t)(nt * 128 + w * 32 + lr) * K + k0 + gc * 8;

    // fragment read setup
    int lm = l & 15, q4 = l >> 4;
    int sw = lm & 7;

    floatx4 acc[4][2] = {};

    for (int s = c0; s < c1; ++s) {
#pragma unroll
        for (int q = 0; q < 2; ++q)
            async_copy16(gA0 + (size_t)q * 8 * K, As + (w * 16 + q * 8) * 64);
#pragma unroll
        for (int q = 0; q < 4; ++q)
            async_copy16(gB0 + (size_t)q * 8 * K, Bs + (w * 32 + q * 8) * 64);
        gA0 += 64; gB0 += 64;
        __syncthreads();
#pragma unroll
        for (int kw = 0; kw < 2; ++kw) {
            int ck = ((kw * 4 + q4) ^ sw) * 8;
            half8v af[4], bf[2];
#pragma unroll
            for (int i = 0; i < 4; ++i)
                af[i] = *(const half8v*)&As[(i * 16 + lm) * 64 + ck];
#pragma unroll
            for (int j = 0; j < 2; ++j)
                bf[j] = *(const half8v*)&Bs[(w * 32 + j * 16 + lm) * 64 + ck];
#pragma unroll
            for (int i = 0; i < 4; ++i)
#pragma unroll
                for (int j = 0; j < 2; ++j)
                    acc[i][j] = __builtin_amdgcn_mfma_f32_16x16x32_f16(af[i], bf[j], acc[i][j], 0, 0, 0);
        }
        __syncthreads();
    }

    // ---- epilogue ----
    // Stage full 64x128 tile in LDS (stride 136 halves), then fully-coalesced
    // 16B/lane stores: 16 lanes cover one 256B output row segment.
    // (loop above ends with __syncthreads -> safe to overwrite staging LDS)
#pragma unroll
    for (int i = 0; i < 4; ++i)
#pragma unroll
        for (int j = 0; j < 2; ++j)
#pragma unroll
            for (int r = 0; r < 4; ++r)
                lds[(i * 16 + q4 * 4 + r) * 136 + w * 32 + j * 16 + lm] = (_Float16)acc[i][j][r];
    __syncthreads();
    _Float16* Cp = Cpart + (size_t)z * (N_NODES * HH);
    int erow = tid >> 4, ecol = (tid & 15) * 8;
    int gm0 = mt * 64, gn0 = nt * 128;
#pragma unroll
    for (int p = 0; p < 4; ++p) {
        int rr = p * 16 + erow;
        half8v v = *(const half8v*)&lds[rr * 136 + ecol];
        *(half8v*)&Cp[(size_t)(gm0 + rr) * HH + gn0 + ecol] = v;
    }
}

// ---------------- conv1 epilogue: split-K reduce + bias1 + relu -> h fp16 ----------------
__global__ __launch_bounds__(256) void hep_k(const _Float16* __restrict__ Cp,
                                             const float* __restrict__ bias,
                                             _Float16* __restrict__ h) {
    int idx = (blockIdx.x * 256 + threadIdx.x) * 8;
    float a[8] = {};
#pragma unroll
    for (int zz = 0; zz < NSL1; ++zz) {
        half8v v = *(const half8v*)(Cp + (size_t)zz * (N_NODES * HH) + idx);
#pragma unroll
        for (int j = 0; j < 8; ++j) a[j] += (float)v[j];
    }
    int col = idx & 255;
    half8v o;
#pragma unroll
    for (int j = 0; j < 8; ++j) o[j] = (_Float16)fmaxf(a[j] + bias[col + j], 0.f);
    *(half8v*)(h + idx) = o;
}

// ---------------- fused: split-K reduce (conv2) + bias2 + mean-pool + readout MLP ----------------
__global__ __launch_bounds__(256) void poolread_k(const _Float16* __restrict__ Cp,
                                                  const int* __restrict__ batch,
                                                  const float* __restrict__ bias2,
                                                  const float* __restrict__ l1w,
                                                  const float* __restrict__ l1b,
                                                  const float* __restrict__ l2w,
                                                  const float* __restrict__ l2b,
                                                  float* __restrict__ out) {
    int g = blockIdx.x, t = threadIdx.x;
    __shared__ int bnds[2];
    __shared__ float sp[256];
    __shared__ float sz[128];
    if (t < 2) {
        int target = g + t;
        int lo = 0, hi = N_NODES;
        while (lo < hi) { int mid = (lo + hi) >> 1; if (batch[mid] < target) lo = mid + 1; else hi = mid; }
        bnds[t] = lo;
    }
    __syncthreads();
    int lo = bnds[0], hi = bnds[1];
    float s = 0.f;
    for (int n = lo; n < hi; ++n) {
#pragma unroll
        for (int zz = 0; zz < NSL2; ++zz)
            s += (float)Cp[(size_t)zz * (N_NODES * HH) + (size_t)n * HH + t];
    }
    sp[t] = (hi > lo) ? (s / (float)(hi - lo) + bias2[t]) : 0.f;
    __syncthreads();
    if (t < 128) {
        float a = l1b[t];
#pragma unroll 8
        for (int i = 0; i < 256; ++i) a += sp[i] * l1w[i * 128 + t];
        sz[t] = fmaxf(a, 0.f) * l2w[t];
    }
    __syncthreads();
    for (int ss = 64; ss > 0; ss >>= 1) {
        if (t < ss) sz[t] += sz[t + ss];
        __syncthreads();
    }
    if (t == 0) {
        float zz = sz[0] + l2b[0];
        out[g] = 1.0f / (1.0f + expf(-zz));
    }
}

extern "C" void kernel_launch(void* const* d_in, const int* in_sizes, int n_in,
                              void* d_out, int out_size, void* d_ws, size_t ws_size,
                              hipStream_t stream) {
    const float* x       = (const float*)d_in[0];
    const int*   ei      = (const int*)d_in[1];
    const float* ea      = (const float*)d_in[2];
    const int*   batch   = (const int*)d_in[3];
    const float* nn1_w   = (const float*)d_in[4];
    const float* nn1_b   = (const float*)d_in[5];
    const float* root1_w = (const float*)d_in[6];
    const float* bias1   = (const float*)d_in[7];
    const float* nn2_w   = (const float*)d_in[8];
    const float* nn2_b   = (const float*)d_in[9];
    const float* root2_w = (const float*)d_in[10];
    const float* bias2   = (const float*)d_in[11];
    const float* lin1_w  = (const float*)d_in[12];
    const float* lin1_b  = (const float*)d_in[13];
    const float* lin2_w  = (const float*)d_in[14];
    const float* lin2_b  = (const float*)d_in[15];
    float* out = (float*)d_out;
    float* ws  = (float*)d_ws;

    _Float16* S   = (_Float16*)(ws + OFF_S);
    _Float16* BT1 = (_Float16*)(ws + OFF_BT1);
    _Float16* BT2 = (_Float16*)(ws + OFF_BT2);
    _Float16* Cp  = (_Float16*)(ws + OFF_CP);
    _Float16* h   = (_Float16*)(ws + OFF_H);
    int* ip     = (int*)(ws + OFF_INT);
    int* starts = ip;            // 4097
    int* elist  = ip + 4100;     // 8192

    const int* srcv = ei;
    const int* dstv = ei + N_EDGES;

    // 1) CSR + weight pack
    prep_k<<<dim3(1 + K1 / 64 + K2 / 64, 4), 256, 0, stream>>>(
        dstv, starts, elist, nn1_w, nn1_b, root1_w, nn2_w, nn2_b, root2_w, BT1, BT2);

    // 2) conv1 staging: S1 [4096 x 2176] fp16
    s1_k<<<4096, 64, 0, stream>>>(x, ea, srcv, starts, elist, S);

    // 3) conv1 GEMM: BM=64 tiles, split-K=8 (1024 blocks = 4/CU)
    gemm_f16<<<dim3(2, 64, NSL1), 256, 0, stream>>>(S, BT1, Cp, K1, K1 / 64, NSL1);

    // 4) reduce + bias1 + relu -> h fp16
    hep_k<<<512, 256, 0, stream>>>(Cp, bias1, h);

    // 5) conv2 staging: S2 [4096 x 8704] fp16
    s2_k<<<4096, 256, 0, stream>>>(h, ea, srcv, starts, elist, S);

    // 6) conv2 GEMM: BM=64 tiles, split-K=10 (1280 blocks = 5/CU)
    gemm_f16<<<dim3(2, 64, NSL2), 256, 0, stream>>>(S, BT2, Cp, K2, K2 / 64, NSL2);

    // 7) reduce + bias2 + mean-pool + MLP + sigmoid
    poolread_k<<<N_GRAPHS, 256, 0, stream>>>(Cp, batch, bias2,
                                             lin1_w, lin1_b, lin2_w, lin2_b, out);
}

// Round 9
// 197.585 us; speedup vs baseline: 1.0228x; 1.0228x over previous
//
#include <hip/hip_runtime.h>
#include <math.h>

#define N_NODES 4096
#define N_EDGES 8192
#define N_GRAPHS 256
#define D_NODE 64
#define D_EDGE 32
#define HH 256

#define K1 2176   // 33*64 (edge-MLP + nn_b rows) + 64 (x augment for root1)
#define K2 8704   // 33*256 + 256 (h augment for root2)
#define NSL1 8    // split-K slices conv1
#define NSL2 12   // split-K slices conv2

typedef _Float16 half8v __attribute__((ext_vector_type(8)));
typedef _Float16 half4v __attribute__((ext_vector_type(4)));
typedef float floatx4 __attribute__((ext_vector_type(4)));

// ---------------- workspace layout (float offsets) ----------------
static const size_t OFF_S    = 0;              // S fp16: 4096 x 8704 halves = 17,825,792 floats (S1 shares)
static const size_t OFF_BT1  = 17825792;       // BT1 fp16: 256 x 2176 halves = 278,528 floats
static const size_t OFF_BT2  = 18104320;       // BT2 fp16: 256 x 8704 halves = 1,114,112 floats
static const size_t OFF_CP   = 19218432;       // Cpart fp16: 12 x 4096 x 256 halves = 6,291,456 floats
static const size_t OFF_H    = 25509888;       // h fp16: 524,288 floats
static const size_t OFF_INT  = 26034176;       // starts[4097] + pad + elist[8192]
// total ~104 MB

// ---------------- prep: CSR build (block 0) + weight pack (other blocks) ----------------
__device__ void csr_body(const int* __restrict__ dst,
                         int* __restrict__ starts,
                         int* __restrict__ elist) {
    __shared__ int cnt[4096];
    __shared__ int ps[256];
    int t = threadIdx.x;
#pragma unroll
    for (int i = 0; i < 16; ++i) cnt[t * 16 + i] = 0;
    __syncthreads();
#pragma unroll
    for (int i = 0; i < 32; ++i) atomicAdd(&cnt[dst[i * 256 + t]], 1);
    __syncthreads();
    int v[16]; int s = 0;
#pragma unroll
    for (int i = 0; i < 16; ++i) { v[i] = cnt[t * 16 + i]; s += v[i]; }
    ps[t] = s;
    __syncthreads();
    for (int off = 1; off < 256; off <<= 1) {
        int tv = (t >= off) ? ps[t - off] : 0;
        __syncthreads();
        ps[t] += tv;
        __syncthreads();
    }
    int excl = ps[t] - s;
#pragma unroll
    for (int i = 0; i < 16; ++i) {
        starts[t * 16 + i] = excl;
        cnt[t * 16 + i] = excl;       // becomes cursor
        excl += v[i];
    }
    if (t == 255) starts[4096] = excl;
    __syncthreads();
#pragma unroll
    for (int i = 0; i < 32; ++i) {
        int e = i * 256 + t;
        int d = dst[e];
        int p = atomicAdd(&cnt[d], 1);
        elist[p] = e;
    }
}

__device__ void packT_body(const float* __restrict__ w,
                           const float* __restrict__ b,
                           const float* __restrict__ rw,
                           _Float16* __restrict__ BT,
                           int kk0, int o0, int K,
                           int wlim, int blim, int wshift, int wmask, int wrow) {
    __shared__ float T[64][65];
    int t = threadIdx.x;
    int ol = t & 63, kb = t >> 6;
#pragma unroll
    for (int p = 0; p < 16; ++p) {
        int kl = p * 4 + kb;
        int kk = kk0 + kl, o = o0 + ol;
        float v;
        if (kk < wlim)      v = w[(kk >> wshift) * wrow + (kk & wmask) * 256 + o];
        else if (kk < blim) v = b[(kk - wlim) * 256 + o];
        else                v = rw[(kk - blim) * 256 + o];
        T[kl][ol] = v;
    }
    __syncthreads();
    int kl2 = t & 63, ob = t >> 6;
#pragma unroll
    for (int p = 0; p < 16; ++p) {
        int ol2 = p * 4 + ob;
        BT[(size_t)(o0 + ol2) * K + kk0 + kl2] = (_Float16)T[kl2][ol2];
    }
}

__global__ __launch_bounds__(256) void prep_k(const int* __restrict__ dst,
                                              int* __restrict__ starts,
                                              int* __restrict__ elist,
                                              const float* __restrict__ w1,
                                              const float* __restrict__ b1,
                                              const float* __restrict__ r1,
                                              const float* __restrict__ w2,
                                              const float* __restrict__ b2,
                                              const float* __restrict__ r2,
                                              _Float16* __restrict__ BT1,
                                              _Float16* __restrict__ BT2) {
    int bx = blockIdx.x, by = blockIdx.y;
    if (bx == 0) {
        if (by == 0) csr_body(dst, starts, elist);
        return;
    }
    int pbx = bx - 1, o0 = by * 64;
    if (pbx < K1 / 64)
        packT_body(w1, b1, r1, BT1, pbx * 64, o0, K1, 2048, 2112, 6, 63, 16384);
    else
        packT_body(w2, b2, r2, BT2, (pbx - K1 / 64) * 64, o0, K2, 8192, 8448, 8, 255, 65536);
}

// ---------------- node outer-product staging: barrier-free, vectorized ----------------
// S1[n, k*64+i] = sum_{e:dst=n} ea'[e,k]*x[src[e],i];  S1[n, 2112+i] = x[n,i]
// block = 64 threads = 8 col-groups (8 cols) x 8 k-groups. kg handles k = kg+8j (j<4);
// kg==0 also k=32 (ea'=1); kg==1 also writes the x-augment copy. No LDS, no barriers.
__global__ __launch_bounds__(64) void s1_k(const float* __restrict__ x,
                                           const float* __restrict__ ea,
                                           const int* __restrict__ src,
                                           const int* __restrict__ starts,
                                           const int* __restrict__ elist,
                                           _Float16* __restrict__ S) {
    int n = blockIdx.x, t = threadIdx.x;
    int cg = t & 7, kg = t >> 3;
    int i0 = cg * 8;
    float acc[5][8] = {};
    int e0 = starts[n], e1 = starts[n + 1];
    for (int ie = e0; ie < e1; ++ie) {
        int e = elist[ie];
        int sn = src[e];
        float4 f0 = *(const float4*)&x[sn * 64 + i0];
        float4 f1 = *(const float4*)&x[sn * 64 + i0 + 4];
        float xv[8] = {f0.x, f0.y, f0.z, f0.w, f1.x, f1.y, f1.z, f1.w};
#pragma unroll
        for (int j = 0; j < 4; ++j) {
            float va = ea[e * 32 + kg + 8 * j];
#pragma unroll
            for (int c = 0; c < 8; ++c) acc[j][c] += va * xv[c];
        }
        if (kg == 0) {
#pragma unroll
            for (int c = 0; c < 8; ++c) acc[4][c] += xv[c];   // k=32, ea'=1
        }
    }
    _Float16* row = S + (size_t)n * K1;
#pragma unroll
    for (int j = 0; j < 4; ++j) {
        int k = kg + 8 * j;
        half8v o;
#pragma unroll
        for (int c = 0; c < 8; ++c) o[c] = (_Float16)acc[j][c];
        *(half8v*)&row[k * 64 + i0] = o;
    }
    if (kg == 0) {
        half8v o;
#pragma unroll
        for (int c = 0; c < 8; ++c) o[c] = (_Float16)acc[4][c];
        *(half8v*)&row[32 * 64 + i0] = o;
    }
    if (kg == 1) {
        float4 f0 = *(const float4*)&x[n * 64 + i0];
        float4 f1 = *(const float4*)&x[n * 64 + i0 + 4];
        half8v o;
        o[0] = (_Float16)f0.x; o[1] = (_Float16)f0.y; o[2] = (_Float16)f0.z; o[3] = (_Float16)f0.w;
        o[4] = (_Float16)f1.x; o[5] = (_Float16)f1.y; o[6] = (_Float16)f1.z; o[7] = (_Float16)f1.w;
        *(half8v*)&row[2112 + i0] = o;
    }
}

// S2[n, k*256+i] = sum_{e:dst=n} ea'[e,k]*h[src[e],i];  S2[n, 8448+i] = h[n,i]
// block = 256 threads = 32 col-groups (8 cols) x 8 k-groups. Same scheme as s1.
__global__ __launch_bounds__(256) void s2_k(const _Float16* __restrict__ h,
                                            const float* __restrict__ ea,
                                            const int* __restrict__ src,
                                            const int* __restrict__ starts,
                                            const int* __restrict__ elist,
                                            _Float16* __restrict__ S) {
    int n = blockIdx.x, t = threadIdx.x;
    int cg = t & 31, kg = t >> 5;
    int i0 = cg * 8;
    float acc[5][8] = {};
    int e0 = starts[n], e1 = starts[n + 1];
    for (int ie = e0; ie < e1; ++ie) {
        int e = elist[ie];
        int sn = src[e];
        half8v hv = *(const half8v*)&h[sn * 256 + i0];
        float xv[8];
#pragma unroll
        for (int c = 0; c < 8; ++c) xv[c] = (float)hv[c];
#pragma unroll
        for (int j = 0; j < 4; ++j) {
            float va = ea[e * 32 + kg + 8 * j];
#pragma unroll
            for (int c = 0; c < 8; ++c) acc[j][c] += va * xv[c];
        }
        if (kg == 0) {
#pragma unroll
            for (int c = 0; c < 8; ++c) acc[4][c] += xv[c];   // k=32, ea'=1
        }
    }
    _Float16* row = S + (size_t)n * K2;
#pragma unroll
    for (int j = 0; j < 4; ++j) {
        int k = kg + 8 * j;
        half8v o;
#pragma unroll
        for (int c = 0; c < 8; ++c) o[c] = (_Float16)acc[j][c];
        *(half8v*)&row[k * 256 + i0] = o;
    }
    if (kg == 0) {
        half8v o;
#pragma unroll
        for (int c = 0; c < 8; ++c) o[c] = (_Float16)acc[4][c];
        *(half8v*)&row[32 * 256 + i0] = o;
    }
    if (kg == 1) {
        half8v hv = *(const half8v*)&h[n * 256 + i0];
        *(half8v*)&row[8448 + i0] = hv;
    }
}

// ---------------- MFMA fp16 GEMM, BK=64, variable split-K, fp16 partials ----------------
// (r7 structure, proven 200.2 us / absmax 0.0049)
__device__ __forceinline__ void async_copy16(const void* g, void* l) {
    __builtin_amdgcn_global_load_lds(
        (__attribute__((address_space(1))) unsigned int*)(g),
        (__attribute__((address_space(3))) unsigned int*)(l), 16, 0, 0);
}

__global__ __launch_bounds__(256, 3) void gemm_f16(const _Float16* __restrict__ A,
                                                   const _Float16* __restrict__ BT,
                                                   _Float16* __restrict__ Cpart,
                                                   int K, int NC, int Z) {
    __shared__ _Float16 lds[17408];     // 34 KB: staging 2x(128x64); epilogue 4x(64x68)
    _Float16* As = lds;
    _Float16* Bs = lds + 128 * 64;
    int tid = threadIdx.x;
    int w = tid >> 6, l = tid & 63;
    int mt = blockIdx.y, nt = blockIdx.x, z = blockIdx.z;
    int c0 = z * NC / Z, c1 = (z + 1) * NC / Z;
    int k0 = c0 * 64;
    int wm = w & 1, wn = w >> 1;

    int lr = l >> 3, lc = l & 7;
    int gc = lc ^ lr;
    const _Float16* gA0 = A  + (size_t)(mt * 128 + w * 32 + lr) * K + k0 + gc * 8;
    const _Float16* gB0 = BT + (size_t)(nt * 128 + w * 32 + lr) * K + k0 + gc * 8;

    int lm = l & 15, q4 = l >> 4;
    int sw = lm & 7;

    floatx4 acc[4][4] = {};

    for (int s = c0; s < c1; ++s) {
#pragma unroll
        for (int q = 0; q < 4; ++q) {
            async_copy16(gA0 + (size_t)q * 8 * K, As + (w * 32 + q * 8) * 64);
            async_copy16(gB0 + (size_t)q * 8 * K, Bs + (w * 32 + q * 8) * 64);
        }
        gA0 += 64; gB0 += 64;
        __syncthreads();
#pragma unroll
        for (int kw = 0; kw < 2; ++kw) {
            int ck = ((kw * 4 + q4) ^ sw) * 8;
            half8v af[4], bf[4];
#pragma unroll
            for (int i = 0; i < 4; ++i)
                af[i] = *(const half8v*)&As[(wm * 64 + i * 16 + lm) * 64 + ck];
#pragma unroll
            for (int j = 0; j < 4; ++j)
                bf[j] = *(const half8v*)&Bs[(wn * 64 + j * 16 + lm) * 64 + ck];
#pragma unroll
            for (int i = 0; i < 4; ++i)
#pragma unroll
                for (int j = 0; j < 4; ++j)
                    acc[i][j] = __builtin_amdgcn_mfma_f32_16x16x32_f16(af[i], bf[j], acc[i][j], 0, 0, 0);
        }
        __syncthreads();
    }

    // coalesced epilogue via LDS
    _Float16* ep = lds + w * 4352;      // 64*68 halves
#pragma unroll
    for (int i = 0; i < 4; ++i)
#pragma unroll
        for (int j = 0; j < 4; ++j)
#pragma unroll
            for (int r = 0; r < 4; ++r)
                ep[(i * 16 + q4 * 4 + r) * 68 + j * 16 + lm] = (_Float16)acc[i][j][r];
    __syncthreads();
    _Float16* Cp = Cpart + (size_t)z * (N_NODES * HH);
    int row8 = l >> 3, colg = (l & 7) * 8;
    int gm0 = mt * 128 + wm * 64, gn0 = nt * 128 + wn * 64;
#pragma unroll
    for (int i8 = 0; i8 < 8; ++i8) {
        int rr = i8 * 8 + row8;
        half4v lo = *(const half4v*)&ep[rr * 68 + colg];
        half4v hi = *(const half4v*)&ep[rr * 68 + colg + 4];
        half8v v;
        v[0] = lo[0]; v[1] = lo[1]; v[2] = lo[2]; v[3] = lo[3];
        v[4] = hi[0]; v[5] = hi[1]; v[6] = hi[2]; v[7] = hi[3];
        *(half8v*)&Cp[(size_t)(gm0 + rr) * HH + gn0 + colg] = v;
    }
}

// ---------------- conv1 epilogue: split-K reduce + bias1 + relu -> h fp16 ----------------
__global__ __launch_bounds__(256) void hep_k(const _Float16* __restrict__ Cp,
                                             const float* __restrict__ bias,
                                             _Float16* __restrict__ h) {
    int idx = (blockIdx.x * 256 + threadIdx.x) * 8;
    float a[8] = {};
#pragma unroll
    for (int zz = 0; zz < NSL1; ++zz) {
        half8v v = *(const half8v*)(Cp + (size_t)zz * (N_NODES * HH) + idx);
#pragma unroll
        for (int j = 0; j < 8; ++j) a[j] += (float)v[j];
    }
    int col = idx & 255;
    half8v o;
#pragma unroll
    for (int j = 0; j < 8; ++j) o[j] = (_Float16)fmaxf(a[j] + bias[col + j], 0.f);
    *(half8v*)(h + idx) = o;
}

// ---------------- fused: split-K reduce (conv2) + bias2 + mean-pool + readout MLP ----------------
__global__ __launch_bounds__(256) void poolread_k(const _Float16* __restrict__ Cp,
                                                  const int* __restrict__ batch,
                                                  const float* __restrict__ bias2,
                                                  const float* __restrict__ l1w,
                                                  const float* __restrict__ l1b,
                                                  const float* __restrict__ l2w,
                                                  const float* __restrict__ l2b,
                                                  float* __restrict__ out) {
    int g = blockIdx.x, t = threadIdx.x;
    __shared__ int bnds[2];
    __shared__ float sp[256];
    __shared__ float sz[128];
    if (t < 2) {
        int target = g + t;
        int lo = 0, hi = N_NODES;
        while (lo < hi) { int mid = (lo + hi) >> 1; if (batch[mid] < target) lo = mid + 1; else hi = mid; }
        bnds[t] = lo;
    }
    __syncthreads();
    int lo = bnds[0], hi = bnds[1];
    float s = 0.f;
    for (int n = lo; n < hi; ++n) {
#pragma unroll
        for (int zz = 0; zz < NSL2; ++zz)
            s += (float)Cp[(size_t)zz * (N_NODES * HH) + (size_t)n * HH + t];
    }
    sp[t] = (hi > lo) ? (s / (float)(hi - lo) + bias2[t]) : 0.f;
    __syncthreads();
    if (t < 128) {
        float a = l1b[t];
#pragma unroll 8
        for (int i = 0; i < 256; ++i) a += sp[i] * l1w[i * 128 + t];
        sz[t] = fmaxf(a, 0.f) * l2w[t];
    }
    __syncthreads();
    for (int ss = 64; ss > 0; ss >>= 1) {
        if (t < ss) sz[t] += sz[t + ss];
        __syncthreads();
    }
    if (t == 0) {
        float zz = sz[0] + l2b[0];
        out[g] = 1.0f / (1.0f + expf(-zz));
    }
}

extern "C" void kernel_launch(void* const* d_in, const int* in_sizes, int n_in,
                              void* d_out, int out_size, void* d_ws, size_t ws_size,
                              hipStream_t stream) {
    const float* x       = (const float*)d_in[0];
    const int*   ei      = (const int*)d_in[1];
    const float* ea      = (const float*)d_in[2];
    const int*   batch   = (const int*)d_in[3];
    const float* nn1_w   = (const float*)d_in[4];
    const float* nn1_b   = (const float*)d_in[5];
    const float* root1_w = (const float*)d_in[6];
    const float* bias1   = (const float*)d_in[7];
    const float* nn2_w   = (const float*)d_in[8];
    const float* nn2_b   = (const float*)d_in[9];
    const float* root2_w = (const float*)d_in[10];
    const float* bias2   = (const float*)d_in[11];
    const float* lin1_w  = (const float*)d_in[12];
    const float* lin1_b  = (const float*)d_in[13];
    const float* lin2_w  = (const float*)d_in[14];
    const float* lin2_b  = (const float*)d_in[15];
    float* out = (float*)d_out;
    float* ws  = (float*)d_ws;

    _Float16* S   = (_Float16*)(ws + OFF_S);
    _Float16* BT1 = (_Float16*)(ws + OFF_BT1);
    _Float16* BT2 = (_Float16*)(ws + OFF_BT2);
    _Float16* Cp  = (_Float16*)(ws + OFF_CP);
    _Float16* h   = (_Float16*)(ws + OFF_H);
    int* ip     = (int*)(ws + OFF_INT);
    int* starts = ip;            // 4097
    int* elist  = ip + 4100;     // 8192

    const int* srcv = ei;
    const int* dstv = ei + N_EDGES;

    // 1) CSR + weight pack
    prep_k<<<dim3(1 + K1 / 64 + K2 / 64, 4), 256, 0, stream>>>(
        dstv, starts, elist, nn1_w, nn1_b, root1_w, nn2_w, nn2_b, root2_w, BT1, BT2);

    // 2) conv1 staging: S1 [4096 x 2176] fp16 (barrier-free, vectorized)
    s1_k<<<4096, 64, 0, stream>>>(x, ea, srcv, starts, elist, S);

    // 3) conv1 GEMM, split-K=8, fp16 partials
    gemm_f16<<<dim3(2, 32, NSL1), 256, 0, stream>>>(S, BT1, Cp, K1, K1 / 64, NSL1);

    // 4) reduce + bias1 + relu -> h fp16
    hep_k<<<512, 256, 0, stream>>>(Cp, bias1, h);

    // 5) conv2 staging: S2 [4096 x 8704] fp16 (barrier-free, vectorized)
    s2_k<<<4096, 256, 0, stream>>>(h, ea, srcv, starts, elist, S);

    // 6) conv2 GEMM, split-K=12, fp16 partials
    gemm_f16<<<dim3(2, 32, NSL2), 256, 0, stream>>>(S, BT2, Cp, K2, K2 / 64, NSL2);

    // 7) reduce + bias2 + mean-pool + MLP + sigmoid
    poolread_k<<<N_GRAPHS, 256, 0, stream>>>(Cp, batch, bias2,
                                             lin1_w, lin1_b, lin2_w, lin2_b, out);
}